// Round 14
// baseline (270.501 us; speedup 1.0000x reference)
//
#include <hip/hip_runtime.h>
#include <hip/hip_bf16.h>
#include <cstdint>

#define MDIM 32768
#define NDIM 1024
#define KDIM 1024
#define KC   512   // compacted K (2:4 structured mask -> 2 of every 4 cols active)

typedef float          f32x4 __attribute__((ext_vector_type(4)));
typedef short          s16x8 __attribute__((ext_vector_type(8)));
typedef unsigned short u16x4 __attribute__((ext_vector_type(4)));
typedef unsigned short u16x8 __attribute__((ext_vector_type(8)));

typedef __attribute__((address_space(1))) unsigned int gu32;
typedef __attribute__((address_space(3))) unsigned int lu32;

// fp32 -> bf16 round-to-nearest-even (inputs are finite; no NaN handling needed)
__device__ __forceinline__ unsigned short f2bf(float f) {
  unsigned int u = __builtin_bit_cast(unsigned int, f);
  u += 0x7fffu + ((u >> 16) & 1u);
  return (unsigned short)(u >> 16);
}

// Branchless 2-of-4 column selection from mask values (exactly 2 of m0..m3 are
// nonzero). Covers all six patterns.
__device__ __forceinline__ float sel_first(f32x4 v, f32x4 m) {
  return m[0] != 0.0f ? v[0] : (m[1] != 0.0f ? v[1] : v[2]);
}
__device__ __forceinline__ float sel_second(f32x4 v, f32x4 m) {
  return m[3] != 0.0f ? v[3] : (m[2] != 0.0f ? v[2] : v[1]);
}

// async global->LDS, 16 bytes per lane (global_load_lds_dwordx4).
__device__ __forceinline__ void async16(const void* g, void* l) {
  __builtin_amdgcn_global_load_lds((gu32*)g, (lu32*)l, 16, 0, 0);
}

// Pass 1 (R0's measured-good form, unchanged): fused compact+convert for X
// and W in one dispatch. ~30 us, at the BW roofline for its ~170 MB.
__global__ __launch_bounds__(256) void compact_kernel(
    const float* __restrict__ x, const float* __restrict__ w,
    const float* __restrict__ msk,
    unsigned short* __restrict__ xb, unsigned short* __restrict__ wb) {
  const long long i = (long long)blockIdx.x * 256 + threadIdx.x;
  const long long nxw = (long long)MDIM * KDIM / 8;  // x windows
  const long long nww = (long long)NDIM * KDIM / 8;  // w windows
  if (i < nxw) {
    const int wi = (int)(i & 127);
    const long long row = i >> 7;
    const float* p = x + row * KDIM + wi * 8;
    f32x4 a = *(const f32x4*)p;
    f32x4 b = *(const f32x4*)(p + 4);
    f32x4 ma = *(const f32x4*)(msk + wi * 8);      // row-0 pattern
    f32x4 mb = *(const f32x4*)(msk + wi * 8 + 4);
    u16x4 o;
    o[0] = f2bf(sel_first(a, ma));
    o[1] = f2bf(sel_second(a, ma));
    o[2] = f2bf(sel_first(b, mb));
    o[3] = f2bf(sel_second(b, mb));
    ((u16x4*)xb)[i] = o;
  } else if (i < nxw + nww) {
    const long long j = i - nxw;
    const int wi = (int)(j & 127);
    const long long row = j >> 7;
    const float* p = w + row * KDIM + wi * 8;
    f32x4 a = *(const f32x4*)p;
    f32x4 b = *(const f32x4*)(p + 4);
    f32x4 moa = *(const f32x4*)(msk + row * KDIM + wi * 8);  // own-row mask
    f32x4 mob = *(const f32x4*)(msk + row * KDIM + wi * 8 + 4);
    f32x4 ma = *(const f32x4*)(msk + wi * 8);                // row-0 pattern
    f32x4 mb = *(const f32x4*)(msk + wi * 8 + 4);
#pragma unroll
    for (int t = 0; t < 4; ++t) { a[t] *= moa[t]; b[t] *= mob[t]; }  // faithful w*mask
    u16x4 o;
    o[0] = f2bf(sel_first(a, ma));
    o[1] = f2bf(sel_second(a, ma));
    o[2] = f2bf(sel_first(b, mb));
    o[3] = f2bf(sel_second(b, mb));
    ((u16x4*)wb)[j] = o;
  }
}

// ---------------------------------------------------------------------------
// Pass 2: C = Xb * Wb^T, 128x128 / 4 waves. Evolution of R12's dbuf (which
// won -6.3 us): ASYMMETRIC pipeline depth + single barrier per iteration.
//
// R12 model update: 1-deep prefetch (~700 cyc cover) hides L2 (~250) but not
// HBM (~900). A-panels: first toucher misses to HBM, and the 8 concurrent
// nt-sharers pile onto the same in-flight miss -> A staging still exposes
// 200-400 cyc/iter. B (Wb, 1 MiB) is L2-resident -> fully covered at depth 1.
//
// Fix: A staged 2 tiles ahead (3-buffer ring, ~1600 cyc cover >= HBM);
// B stays 1 ahead (2 buffers). ONE barrier per iteration:
//   vmcnt(4)  -- waits A(kt),B(kt); only A(kt+1)'s 4 loads are newer
//   s_barrier -- all waves certified tile kt landed
//   issue B(kt+1) -> bb[(kt+1)&1], A(kt+2) -> ab[(kt+2)%3]
//   compute from ab[kt%3], bb[kt&1]
// WAR safety: each stage targets a buffer whose last readers ran in
// compute(kt-1), which precedes every wave's arrival at THIS iteration's
// barrier; stages are issued after that barrier. Stage targets are disjoint
// from compute(kt)'s buffers ((kt+2)%3 != kt%3, (kt+1)&1 != kt&1).
// Queue accounting (per-wave FIFO, 4 loads/group): at the wait point the
// outstanding groups are A(kt), B(kt), A(kt+1) -> vmcnt(4) retires A(kt),B(kt).
// kt=7 drains with vmcnt(0). LDS 3*16+2*16 = 80 KiB -> still 2 blocks/CU
// (occupancy unchanged vs R12 -> clean isolation of depth + barrier count).
// Numerics identical to R0/R12 (same fragments, same MFMA order).
// ---------------------------------------------------------------------------
__global__ __launch_bounds__(256) void gemm_db3_kernel(
    const unsigned short* __restrict__ Ab, const unsigned short* __restrict__ Bb,
    float* __restrict__ C) {
  __shared__ __align__(16) unsigned short lA[3][128 * 64];  // 3 x 16 KiB ring
  __shared__ __align__(16) unsigned short lB[2][128 * 64];  // 2 x 16 KiB

  const int tid = threadIdx.x;
  // XCD swizzle (R0's exact mapping): 2048 blocks, %8==0 -> bijective.
  const int g = blockIdx.x;
  const int xcd = g & 7;
  const int local = g >> 3;
  const int nt = local & 7;
  const int mt = xcd * 32 + (local >> 3);
  const int m0 = mt * 128, n0 = nt * 128;
  const int lane = tid & 63;
  const int wv = tid >> 6;
  const int q = lane >> 4, r = lane & 15;
  const int wm = (wv >> 1) * 64, wn = (wv & 1) * 64;

  f32x4 acc[4][4] = {};

  int prow[4], pcg[4];
#pragma unroll
  for (int i = 0; i < 4; ++i) {
    const int p = i * 256 + tid;
    prow[i] = p >> 3;
    pcg[i] = (p & 7) ^ (prow[i] & 7);
  }

  auto stageA = [&](int kt, int buf) {
    const int k0 = kt * 64;
#pragma unroll
    for (int i = 0; i < 4; ++i) {
      const int p = i * 256 + tid;
      async16(Ab + (size_t)(m0 + prow[i]) * KC + k0 + pcg[i] * 8, &lA[buf][p * 8]);
    }
  };
  auto stageB = [&](int kt, int buf) {
    const int k0 = kt * 64;
#pragma unroll
    for (int i = 0; i < 4; ++i) {
      const int p = i * 256 + tid;
      async16(Bb + (size_t)(n0 + prow[i]) * KC + k0 + pcg[i] * 8, &lB[buf][p * 8]);
    }
  };

  // prologue: queue = A(0), B(0), A(1)  (issue order matters for vmcnt math)
  stageA(0, 0);
  stageB(0, 0);
  stageA(1, 1);

  for (int kt = 0; kt < 8; ++kt) {
    if (kt < 7) {
      // outstanding groups here: A(kt), B(kt), A(kt+1)  -> wait oldest two
      asm volatile("s_waitcnt vmcnt(4)" ::: "memory");
    } else {
      asm volatile("s_waitcnt vmcnt(0)" ::: "memory");
    }
    __builtin_amdgcn_s_barrier();       // all waves: tile kt fully landed;
                                        // all reads of compute(kt-1) done
    __builtin_amdgcn_sched_barrier(0);  // no hoisting across the barrier

    // prefetch: B one ahead (L2-resident), A two ahead (covers HBM miss)
    if (kt < 7) stageB(kt + 1, (kt + 1) & 1);
    if (kt < 6) stageA(kt + 2, (kt + 2) % 3);

    const unsigned short* sA = &lA[kt % 3][0];
    const unsigned short* sB = &lB[kt & 1][0];
#pragma unroll
    for (int kk = 0; kk < 2; ++kk) {
      s16x8 av[4], bv[4];
#pragma unroll
      for (int i = 0; i < 4; ++i) {
        const int ar = wm + 16 * i + r;
        av[i] = *(const s16x8*)&sA[ar * 64 + (((kk << 2) | q) ^ (ar & 7)) * 8];
        const int br = wn + 16 * i + r;
        bv[i] = *(const s16x8*)&sB[br * 64 + (((kk << 2) | q) ^ (br & 7)) * 8];
      }
#pragma unroll
      for (int i = 0; i < 4; ++i)
#pragma unroll
        for (int j = 0; j < 4; ++j)
          acc[i][j] = __builtin_amdgcn_mfma_f32_16x16x32_bf16(bv[j], av[i],
                                                              acc[i][j], 0, 0, 0);
    }
    __builtin_amdgcn_sched_barrier(0);  // keep ds_reads inside their phase
  }

  // epilogue (transposed fragment, verified mapping, identical to R0)
#pragma unroll
  for (int i = 0; i < 4; ++i) {
    const size_t rowoff = (size_t)(m0 + wm + 16 * i + r) * NDIM;
#pragma unroll
    for (int j = 0; j < 4; ++j) {
      const int col = n0 + wn + 16 * j + 4 * q;
      *(f32x4*)&C[rowoff + col] = acc[i][j];
    }
  }
}

// ---------------------------------------------------------------------------
// Fallback (ws too small): dense K=1024 GEMM, unchanged.
// ---------------------------------------------------------------------------
__global__ __launch_bounds__(256) void gemm_dense_kernel(
    const float* __restrict__ Af, const float* __restrict__ Wf,
    const float* __restrict__ Mf, float* __restrict__ C) {
  __shared__ __align__(16) unsigned short lA[128 * 64];
  __shared__ __align__(16) unsigned short lB[128 * 64];

  constexpr int kstr = KDIM;
  constexpr int kiters = kstr / 64;

  const int tid = threadIdx.x;
  const int g = blockIdx.x;  // 2048 blocks
  const int xcd = g & 7;
  const int local = g >> 3;
  const int nt = local & 7;
  const int mt = xcd * 32 + (local >> 3);
  const int m0 = mt * 128, n0 = nt * 128;
  const int lane = tid & 63;
  const int wv = tid >> 6;
  const int q = lane >> 4, r = lane & 15;
  const int wm = (wv >> 1) * 64, wn = (wv & 1) * 64;

  f32x4 acc[4][4] = {};

  int prow[4], pcg[4];
#pragma unroll
  for (int i = 0; i < 4; ++i) {
    const int p = i * 256 + tid;
    prow[i] = p >> 3;
    pcg[i] = (p & 7) ^ (prow[i] & 7);
  }

  for (int kt = 0; kt < kiters; ++kt) {
    const int k0 = kt * 64;
#pragma unroll
    for (int i = 0; i < 4; ++i) {
      const int p = i * 256 + tid;
      const size_t offA = (size_t)(m0 + prow[i]) * kstr + k0 + pcg[i] * 8;
      const size_t offB = (size_t)(n0 + prow[i]) * kstr + k0 + pcg[i] * 8;
      f32x4 a0 = *(const f32x4*)(Af + offA);
      f32x4 a1 = *(const f32x4*)(Af + offA + 4);
      f32x4 w0 = *(const f32x4*)(Wf + offB);
      f32x4 w1 = *(const f32x4*)(Wf + offB + 4);
      f32x4 k0v = *(const f32x4*)(Mf + offB);
      f32x4 k1v = *(const f32x4*)(Mf + offB + 4);
      u16x8 oa, ob;
#pragma unroll
      for (int t = 0; t < 4; ++t) {
        oa[t] = f2bf(a0[t]); oa[4 + t] = f2bf(a1[t]);
        ob[t] = f2bf(w0[t] * k0v[t]); ob[4 + t] = f2bf(w1[t] * k1v[t]);
      }
      *(u16x8*)&lA[p * 8] = oa;
      *(u16x8*)&lB[p * 8] = ob;
    }
    __syncthreads();
#pragma unroll
    for (int kk = 0; kk < 2; ++kk) {
      s16x8 av[4], bv[4];
#pragma unroll
      for (int i = 0; i < 4; ++i) {
        const int ar = wm + 16 * i + r;
        av[i] = *(const s16x8*)&lA[ar * 64 + (((kk << 2) | q) ^ (ar & 7)) * 8];
        const int br = wn + 16 * i + r;
        bv[i] = *(const s16x8*)&lB[br * 64 + (((kk << 2) | q) ^ (br & 7)) * 8];
      }
#pragma unroll
      for (int i = 0; i < 4; ++i)
#pragma unroll
        for (int j = 0; j < 4; ++j)
          acc[i][j] = __builtin_amdgcn_mfma_f32_16x16x32_bf16(bv[j], av[i],
                                                              acc[i][j], 0, 0, 0);
    }
    __syncthreads();
  }

#pragma unroll
  for (int i = 0; i < 4; ++i) {
    const size_t rowoff = (size_t)(m0 + wm + 16 * i + r) * NDIM;
#pragma unroll
    for (int j = 0; j < 4; ++j) {
      const int col = n0 + wn + 16 * j + 4 * q;
      *(f32x4*)&C[rowoff + col] = acc[i][j];
    }
  }
}

extern "C" void kernel_launch(void* const* d_in, const int* in_sizes, int n_in,
                              void* d_out, int out_size, void* d_ws, size_t ws_size,
                              hipStream_t stream) {
  (void)in_sizes; (void)n_in; (void)out_size;
  const float* x  = (const float*)d_in[0];
  const float* w  = (const float*)d_in[1];
  const float* mk = (const float*)d_in[2];
  float* out = (float*)d_out;

  const size_t xb_bytes = (size_t)MDIM * KC * 2;  // 32 MiB
  const size_t wb_bytes = (size_t)NDIM * KC * 2;  // 1 MiB

  if (ws_size >= xb_bytes + wb_bytes) {
    unsigned short* xb = (unsigned short*)d_ws;
    unsigned short* wb = (unsigned short*)((char*)d_ws + xb_bytes);
    const long long totw = ((long long)MDIM * KDIM + (long long)NDIM * KDIM) / 8;
    const int cblocks = (int)((totw + 255) / 256);
    hipLaunchKernelGGL(compact_kernel, dim3(cblocks), dim3(256), 0, stream,
                       x, w, mk, xb, wb);
    const int gemm_blocks = (MDIM / 128) * (NDIM / 128);  // 2048
    hipLaunchKernelGGL(gemm_db3_kernel, dim3(gemm_blocks), dim3(256), 0, stream,
                       xb, wb, out);
  } else {
    const int gemm_blocks = (MDIM / 128) * (NDIM / 128);  // 2048
    hipLaunchKernelGGL(gemm_dense_kernel, dim3(gemm_blocks), dim3(256), 0, stream,
                       x, w, mk, out);
  }
}

// Round 15
// 269.502 us; speedup vs baseline: 1.0037x; 1.0037x over previous
//
#include <hip/hip_runtime.h>
#include <hip/hip_bf16.h>
#include <cstdint>

#define MDIM 32768
#define NDIM 1024
#define KDIM 1024
#define KC   512   // compacted K (2:4 structured mask -> 2 of every 4 cols active)

typedef float          f32x4 __attribute__((ext_vector_type(4)));
typedef short          s16x8 __attribute__((ext_vector_type(8)));
typedef unsigned short u16x4 __attribute__((ext_vector_type(4)));
typedef unsigned short u16x8 __attribute__((ext_vector_type(8)));

typedef __attribute__((address_space(1))) unsigned int gu32;
typedef __attribute__((address_space(3))) unsigned int lu32;

// fp32 -> bf16 round-to-nearest-even (inputs are finite; no NaN handling needed)
__device__ __forceinline__ unsigned short f2bf(float f) {
  unsigned int u = __builtin_bit_cast(unsigned int, f);
  u += 0x7fffu + ((u >> 16) & 1u);
  return (unsigned short)(u >> 16);
}

// Branchless 2-of-4 column selection from mask values (exactly 2 of m0..m3 are
// nonzero). Covers all six patterns.
__device__ __forceinline__ float sel_first(f32x4 v, f32x4 m) {
  return m[0] != 0.0f ? v[0] : (m[1] != 0.0f ? v[1] : v[2]);
}
__device__ __forceinline__ float sel_second(f32x4 v, f32x4 m) {
  return m[3] != 0.0f ? v[3] : (m[2] != 0.0f ? v[2] : v[1]);
}

// async global->LDS, 16 bytes per lane (global_load_lds_dwordx4).
__device__ __forceinline__ void async16(const void* g, void* l) {
  __builtin_amdgcn_global_load_lds((gu32*)g, (lu32*)l, 16, 0, 0);
}

// Pass 1 (R0's measured-good form, unchanged): fused compact+convert for X
// and W in one dispatch. ~30 us, at the BW roofline for its ~170 MB.
__global__ __launch_bounds__(256) void compact_kernel(
    const float* __restrict__ x, const float* __restrict__ w,
    const float* __restrict__ msk,
    unsigned short* __restrict__ xb, unsigned short* __restrict__ wb) {
  const long long i = (long long)blockIdx.x * 256 + threadIdx.x;
  const long long nxw = (long long)MDIM * KDIM / 8;  // x windows
  const long long nww = (long long)NDIM * KDIM / 8;  // w windows
  if (i < nxw) {
    const int wi = (int)(i & 127);
    const long long row = i >> 7;
    const float* p = x + row * KDIM + wi * 8;
    f32x4 a = *(const f32x4*)p;
    f32x4 b = *(const f32x4*)(p + 4);
    f32x4 ma = *(const f32x4*)(msk + wi * 8);      // row-0 pattern
    f32x4 mb = *(const f32x4*)(msk + wi * 8 + 4);
    u16x4 o;
    o[0] = f2bf(sel_first(a, ma));
    o[1] = f2bf(sel_second(a, ma));
    o[2] = f2bf(sel_first(b, mb));
    o[3] = f2bf(sel_second(b, mb));
    ((u16x4*)xb)[i] = o;
  } else if (i < nxw + nww) {
    const long long j = i - nxw;
    const int wi = (int)(j & 127);
    const long long row = j >> 7;
    const float* p = w + row * KDIM + wi * 8;
    f32x4 a = *(const f32x4*)p;
    f32x4 b = *(const f32x4*)(p + 4);
    f32x4 moa = *(const f32x4*)(msk + row * KDIM + wi * 8);  // own-row mask
    f32x4 mob = *(const f32x4*)(msk + row * KDIM + wi * 8 + 4);
    f32x4 ma = *(const f32x4*)(msk + wi * 8);                // row-0 pattern
    f32x4 mb = *(const f32x4*)(msk + wi * 8 + 4);
#pragma unroll
    for (int t = 0; t < 4; ++t) { a[t] *= moa[t]; b[t] *= mob[t]; }  // faithful w*mask
    u16x4 o;
    o[0] = f2bf(sel_first(a, ma));
    o[1] = f2bf(sel_second(a, ma));
    o[2] = f2bf(sel_first(b, mb));
    o[3] = f2bf(sel_second(b, mb));
    ((u16x4*)wb)[j] = o;
  }
}

// ---------------------------------------------------------------------------
// Pass 2: C = Xb * Wb^T, 128x128 / 4 waves -- R12's measured-best dbuf
// structure (268.4 us total) with ONE added variable: T5 s_setprio around the
// MFMA clusters.
//
// Status of the pipeline arc: R12 dbuf+vmcnt(8) won -6.3 us; R14's depth-2
// ring was neutral (within cross-run noise) -> fetch latency is fully covered
// at depth 1; residual GEMM time is in-phase ds_read->MFMA serialization with
// only 4 waves/SIMD. setprio regime check (catalog T5): null on lockstep
// single-phase (m190), pays when waves on a CU have role diversity (m191
// attn's independent blocks +4-7%). Here: counted-vmcnt splits stage-issuing
// vs MFMA-entering roles, and 2 independent blocks/CU sit at uncorrelated
// K-iters -> the attn-like case. setprio(1) biases the CU scheduler toward
// the MFMA-issuing wave while the other block's waves issue staging.
//
// Sync invariants (unchanged from R12, verified by 268.4 pass):
//  - vmcnt(8) then s_barrier: tile kt's 8 loads landed in all waves.
//  - end-of-iter s_barrier: readers of buf[cur] done before next stage.
//  - numerics identical to R0 (same fragments, same MFMA order).
// ---------------------------------------------------------------------------
__global__ __launch_bounds__(256) void gemm_db_kernel(
    const unsigned short* __restrict__ Ab, const unsigned short* __restrict__ Bb,
    float* __restrict__ C) {
  __shared__ __align__(16) unsigned short lA[2][128 * 64];  // 2 x 16 KiB
  __shared__ __align__(16) unsigned short lB[2][128 * 64];  // 2 x 16 KiB

  const int tid = threadIdx.x;
  // XCD swizzle (R0's exact mapping): 2048 blocks, %8==0 -> bijective.
  const int g = blockIdx.x;
  const int xcd = g & 7;
  const int local = g >> 3;
  const int nt = local & 7;
  const int mt = xcd * 32 + (local >> 3);
  const int m0 = mt * 128, n0 = nt * 128;
  const int lane = tid & 63;
  const int wv = tid >> 6;
  const int q = lane >> 4, r = lane & 15;
  const int wm = (wv >> 1) * 64, wn = (wv & 1) * 64;

  f32x4 acc[4][4] = {};

  int prow[4], pcg[4];
#pragma unroll
  for (int i = 0; i < 4; ++i) {
    const int p = i * 256 + tid;
    prow[i] = p >> 3;
    pcg[i] = (p & 7) ^ (prow[i] & 7);
  }

  // stage one K-tile (8 global_load_lds instructions per wave)
  auto stage = [&](int kt, int buf) {
    const int k0 = kt * 64;
#pragma unroll
    for (int i = 0; i < 4; ++i) {
      const int p = i * 256 + tid;
      async16(Bb + (size_t)(n0 + prow[i]) * KC + k0 + pcg[i] * 8, &lB[buf][p * 8]);
      async16(Ab + (size_t)(m0 + prow[i]) * KC + k0 + pcg[i] * 8, &lA[buf][p * 8]);
    }
  };

  stage(0, 0);  // prologue

  for (int kt = 0; kt < 8; ++kt) {
    const int cur = kt & 1;
    if (kt < 7) {
      stage(kt + 1, cur ^ 1);  // prefetch next tile; stays in flight
      // wait only for tile kt's 8 loads (the 8 oldest); 8 newest remain.
      asm volatile("s_waitcnt vmcnt(8)" ::: "memory");
    } else {
      asm volatile("s_waitcnt vmcnt(0)" ::: "memory");
    }
    __builtin_amdgcn_s_barrier();       // all waves: tile kt fully landed
    __builtin_amdgcn_sched_barrier(0);  // no hoisting of ds_reads above

    const unsigned short* sA = &lA[cur][0];
    const unsigned short* sB = &lB[cur][0];
#pragma unroll
    for (int kk = 0; kk < 2; ++kk) {
      s16x8 av[4], bv[4];
#pragma unroll
      for (int i = 0; i < 4; ++i) {
        const int ar = wm + 16 * i + r;
        av[i] = *(const s16x8*)&sA[ar * 64 + (((kk << 2) | q) ^ (ar & 7)) * 8];
        const int br = wn + 16 * i + r;
        bv[i] = *(const s16x8*)&sB[br * 64 + (((kk << 2) | q) ^ (br & 7)) * 8];
      }
      __builtin_amdgcn_s_setprio(1);    // T5: favor this wave's MFMA cluster
#pragma unroll
      for (int i = 0; i < 4; ++i)
#pragma unroll
        for (int j = 0; j < 4; ++j)
          acc[i][j] = __builtin_amdgcn_mfma_f32_16x16x32_bf16(bv[j], av[i],
                                                              acc[i][j], 0, 0, 0);
      __builtin_amdgcn_s_setprio(0);
    }
    __builtin_amdgcn_sched_barrier(0);  // no sinking of ds_reads below
    __builtin_amdgcn_s_barrier();       // readers done before buf[cur] is
  }                                     // overwritten by next iter's stage

  // epilogue (transposed fragment, verified mapping, identical to R0)
#pragma unroll
  for (int i = 0; i < 4; ++i) {
    const size_t rowoff = (size_t)(m0 + wm + 16 * i + r) * NDIM;
#pragma unroll
    for (int j = 0; j < 4; ++j) {
      const int col = n0 + wn + 16 * j + 4 * q;
      *(f32x4*)&C[rowoff + col] = acc[i][j];
    }
  }
}

// ---------------------------------------------------------------------------
// Fallback (ws too small): dense K=1024 GEMM, unchanged.
// ---------------------------------------------------------------------------
__global__ __launch_bounds__(256) void gemm_dense_kernel(
    const float* __restrict__ Af, const float* __restrict__ Wf,
    const float* __restrict__ Mf, float* __restrict__ C) {
  __shared__ __align__(16) unsigned short lA[128 * 64];
  __shared__ __align__(16) unsigned short lB[128 * 64];

  constexpr int kstr = KDIM;
  constexpr int kiters = kstr / 64;

  const int tid = threadIdx.x;
  const int g = blockIdx.x;  // 2048 blocks
  const int xcd = g & 7;
  const int local = g >> 3;
  const int nt = local & 7;
  const int mt = xcd * 32 + (local >> 3);
  const int m0 = mt * 128, n0 = nt * 128;
  const int lane = tid & 63;
  const int wv = tid >> 6;
  const int q = lane >> 4, r = lane & 15;
  const int wm = (wv >> 1) * 64, wn = (wv & 1) * 64;

  f32x4 acc[4][4] = {};

  int prow[4], pcg[4];
#pragma unroll
  for (int i = 0; i < 4; ++i) {
    const int p = i * 256 + tid;
    prow[i] = p >> 3;
    pcg[i] = (p & 7) ^ (prow[i] & 7);
  }

  for (int kt = 0; kt < kiters; ++kt) {
    const int k0 = kt * 64;
#pragma unroll
    for (int i = 0; i < 4; ++i) {
      const int p = i * 256 + tid;
      const size_t offA = (size_t)(m0 + prow[i]) * kstr + k0 + pcg[i] * 8;
      const size_t offB = (size_t)(n0 + prow[i]) * kstr + k0 + pcg[i] * 8;
      f32x4 a0 = *(const f32x4*)(Af + offA);
      f32x4 a1 = *(const f32x4*)(Af + offA + 4);
      f32x4 w0 = *(const f32x4*)(Wf + offB);
      f32x4 w1 = *(const f32x4*)(Wf + offB + 4);
      f32x4 k0v = *(const f32x4*)(Mf + offB);
      f32x4 k1v = *(const f32x4*)(Mf + offB + 4);
      u16x8 oa, ob;
#pragma unroll
      for (int t = 0; t < 4; ++t) {
        oa[t] = f2bf(a0[t]); oa[4 + t] = f2bf(a1[t]);
        ob[t] = f2bf(w0[t] * k0v[t]); ob[4 + t] = f2bf(w1[t] * k1v[t]);
      }
      *(u16x8*)&lA[p * 8] = oa;
      *(u16x8*)&lB[p * 8] = ob;
    }
    __syncthreads();
#pragma unroll
    for (int kk = 0; kk < 2; ++kk) {
      s16x8 av[4], bv[4];
#pragma unroll
      for (int i = 0; i < 4; ++i) {
        const int ar = wm + 16 * i + r;
        av[i] = *(const s16x8*)&lA[ar * 64 + (((kk << 2) | q) ^ (ar & 7)) * 8];
        const int br = wn + 16 * i + r;
        bv[i] = *(const s16x8*)&lB[br * 64 + (((kk << 2) | q) ^ (br & 7)) * 8];
      }
#pragma unroll
      for (int i = 0; i < 4; ++i)
#pragma unroll
        for (int j = 0; j < 4; ++j)
          acc[i][j] = __builtin_amdgcn_mfma_f32_16x16x32_bf16(bv[j], av[i],
                                                              acc[i][j], 0, 0, 0);
    }
    __syncthreads();
  }

#pragma unroll
  for (int i = 0; i < 4; ++i) {
    const size_t rowoff = (size_t)(m0 + wm + 16 * i + r) * NDIM;
#pragma unroll
    for (int j = 0; j < 4; ++j) {
      const int col = n0 + wn + 16 * j + 4 * q;
      *(f32x4*)&C[rowoff + col] = acc[i][j];
    }
  }
}

extern "C" void kernel_launch(void* const* d_in, const int* in_sizes, int n_in,
                              void* d_out, int out_size, void* d_ws, size_t ws_size,
                              hipStream_t stream) {
  (void)in_sizes; (void)n_in; (void)out_size;
  const float* x  = (const float*)d_in[0];
  const float* w  = (const float*)d_in[1];
  const float* mk = (const float*)d_in[2];
  float* out = (float*)d_out;

  const size_t xb_bytes = (size_t)MDIM * KC * 2;  // 32 MiB
  const size_t wb_bytes = (size_t)NDIM * KC * 2;  // 1 MiB

  if (ws_size >= xb_bytes + wb_bytes) {
    unsigned short* xb = (unsigned short*)d_ws;
    unsigned short* wb = (unsigned short*)((char*)d_ws + xb_bytes);
    const long long totw = ((long long)MDIM * KDIM + (long long)NDIM * KDIM) / 8;
    const int cblocks = (int)((totw + 255) / 256);
    hipLaunchKernelGGL(compact_kernel, dim3(cblocks), dim3(256), 0, stream,
                       x, w, mk, xb, wb);
    const int gemm_blocks = (MDIM / 128) * (NDIM / 128);  // 2048
    hipLaunchKernelGGL(gemm_db_kernel, dim3(gemm_blocks), dim3(256), 0, stream,
                       xb, wb, out);
  } else {
    const int gemm_blocks = (MDIM / 128) * (NDIM / 128);  // 2048
    hipLaunchKernelGGL(gemm_dense_kernel, dim3(gemm_blocks), dim3(256), 0, stream,
                       x, w, mk, out);
  }
}